// Round 2
// baseline (657.882 us; speedup 1.0000x reference)
//
#include <hip/hip_runtime.h>
#include <hip/hip_bf16.h>
#include <math.h>

#define NNODES 8192
#define NEDGES 98304

#define TPNORM 0.20412414523193154f      // 1/sqrt(24)
#define INV_SQRT8 0.35355339059327373f   // 1/sqrt(8)
#define QT0S (1.0f/24.0f)                // dot-norm * tp-norm folded
#define QT1S 0.024056261216234406f       // 1/(24*sqrt(3))
#define EMB_C 26.6692997f                // 1.14136*e^2*sqrt(10)
#define STEPI 3.6666666666666665f        // 11/3

// ---- f32 workspace layout (element offsets) ----
#define WS_NF    0
#define WS_POS   327680
#define WS_WQ0   352256
#define WS_WQ1   352512
#define WS_FCK1  352576
#define WS_FCK2  352896
#define WS_FCV1  371328
#define WS_FCV2  371648
#define WS_WD00  390080
#define WS_WD11  390336
#define WS_FCP1  390400
#define WS_FCP2  391040
#define WS_CVT_END 464768
#define WS_FLAG  464768
#define WS_NODEX 464784
#define WS_NODEQ 792464
#define WS_Z     1120144
#define WS_EXPV  1128336
#define WS_ATT   1226640
#define WS_POT3  1554320
// total 1578896 floats = 6.32 MB

__device__ __forceinline__ float sus_f(float x){
    return x > 0.f ? __expf(-__fdividef(1.f, x)) : 0.f;
}

__device__ __forceinline__ void edge_geom(const float* __restrict__ pos,
                                          int s, int d,
                                          float su[3], float emb[10], float& cut)
{
    float ev[3];
#pragma unroll
    for (int c = 0; c < 3; ++c)
        ev[c] = pos[s*3+c] - pos[d*3+c];
    float l2 = ev[0]*ev[0] + ev[1]*ev[1] + ev[2]*ev[2] + 1e-12f;
    float elen = sqrtf(l2);
    float inv = __fdividef(1.f, elen);
#pragma unroll
    for (int c = 0; c < 3; ++c) su[c] = ev[c]*inv;
    float le = elen * STEPI;
#pragma unroll
    for (int k = 0; k < 10; ++k){
        float diff = le - (float)(k+1);
        emb[k] = EMB_C * sus_f(diff + 1.f) * sus_f(1.f - diff);
    }
    cut = sus_f(10.f * (1.f - elen*(1.f/3.f)));
}

// ---------------- K0: dtype detection ----------------
// Wq0 is 256 samples of N(0,1). Under the CORRECT interpretation nearly all
// values land in (1e-3, 64); under the wrong one, exponent bits come from
// mantissa garbage -> mostly out of range. Margins: bf16-data -> cb~255,
// f32-data -> cb~136 (odd elements alias the f32 high halves). Threshold 200.
__global__ void k_detect(const void* __restrict__ wq0raw, int* __restrict__ flag)
{
    __shared__ int cb;
    if (threadIdx.x == 0) cb = 0;
    __syncthreads();
    int t = threadIdx.x;   // 256 threads
    const unsigned short* ph = (const unsigned short*)wq0raw;
    unsigned int bits = ((unsigned int)ph[t]) << 16;
    float v = __uint_as_float(bits);
    float a = fabsf(v);
    if (v == v && a > 1e-3f && a < 64.f) atomicAdd(&cb, 1);
    __syncthreads();
    if (threadIdx.x == 0) *flag = (cb >= 200) ? 1 : 0;
}

// ---------------- K0b: convert all float inputs to f32 in ws ----------------
__global__ __launch_bounds__(256)
void k_convert_all(const void* __restrict__ nf,   const void* __restrict__ pos,
                   const void* __restrict__ wq0,  const void* __restrict__ wq1,
                   const void* __restrict__ fck1, const void* __restrict__ fck2,
                   const void* __restrict__ fcv1, const void* __restrict__ fcv2,
                   const void* __restrict__ wd00, const void* __restrict__ wd11,
                   const void* __restrict__ fcp1, const void* __restrict__ fcp2,
                   const int* __restrict__ flag,  float* __restrict__ dst)
{
    int idx = blockIdx.x*256 + threadIdx.x;
    if (idx >= WS_CVT_END) return;
    int isb = *flag;
    const void* src; int local;
    if      (idx < WS_POS)  { src = nf;   local = idx; }
    else if (idx < WS_WQ0)  { src = pos;  local = idx - WS_POS; }
    else if (idx < WS_WQ1)  { src = wq0;  local = idx - WS_WQ0; }
    else if (idx < WS_FCK1) { src = wq1;  local = idx - WS_WQ1; }
    else if (idx < WS_FCK2) { src = fck1; local = idx - WS_FCK1; }
    else if (idx < WS_FCV1) { src = fck2; local = idx - WS_FCK2; }
    else if (idx < WS_FCV2) { src = fcv1; local = idx - WS_FCV1; }
    else if (idx < WS_WD00) { src = fcv2; local = idx - WS_FCV2; }
    else if (idx < WS_WD11) { src = wd00; local = idx - WS_WD00; }
    else if (idx < WS_FCP1) { src = wd11; local = idx - WS_WD11; }
    else if (idx < WS_FCP2) { src = fcp1; local = idx - WS_FCP1; }
    else                    { src = fcp2; local = idx - WS_FCP2; }
    float v;
    if (isb){
        unsigned short u = ((const unsigned short*)src)[local];
        v = __uint_as_float(((unsigned int)u) << 16);
    } else {
        v = ((const float*)src)[local];
    }
    dst[idx] = v;
}

// ---------------- K1: node prep ----------------
__global__ __launch_bounds__(256)
void k_node_prep(const float* __restrict__ ws)
{
    __shared__ float q0w[256], d00[256], q1w[64], d11[64];
    int tid = threadIdx.x;
    q0w[tid] = ws[WS_WQ0 + tid];
    d00[tid] = ws[WS_WD00 + tid];
    if (tid < 64){ q1w[tid] = ws[WS_WQ1 + tid]; d11[tid] = ws[WS_WD11 + tid]; }
    __syncthreads();
    int n = blockIdx.x*256 + tid;
    const float* fb = ws + WS_NF + n*40;
    float x0[16], x1[24];
#pragma unroll
    for (int i=0;i<16;i++) x0[i]=fb[i];
#pragma unroll
    for (int i=0;i<24;i++) x1[i]=fb[16+i];
    float q0[16];
#pragma unroll
    for (int o=0;o<16;o++){
        float a=0.f;
#pragma unroll
        for (int i=0;i<16;i++) a += x0[i]*q0w[i*16+o];
        q0[o] = 0.25f*a;
    }
    float q1[24];
#pragma unroll
    for (int o=0;o<8;o++){
        float a0=0.f,a1=0.f,a2=0.f;
#pragma unroll
        for (int i=0;i<8;i++){
            float w = q1w[i*8+o];
            a0 += x1[i*3+0]*w; a1 += x1[i*3+1]*w; a2 += x1[i*3+2]*w;
        }
        q1[o*3+0]=INV_SQRT8*a0; q1[o*3+1]=INV_SQRT8*a1; q1[o*3+2]=INV_SQRT8*a2;
    }
    float* xb = (float*)(ws + WS_NODEX) + n*40;
#pragma unroll
    for (int i=0;i<16;i++) xb[i]=x0[i];
#pragma unroll
    for (int i=0;i<24;i++) xb[16+i]=x1[i];
    float* qb = (float*)(ws + WS_NODEQ) + n*40;
#pragma unroll
    for (int j=0;j<16;j++){
        float a=0.f;
#pragma unroll
        for (int i=0;i<16;i++) a += q0[i]*d00[i*16+j];
        qb[j] = QT0S*a;
    }
#pragma unroll
    for (int j=0;j<8;j++){
        float a0=0.f,a1=0.f,a2=0.f;
#pragma unroll
        for (int i=0;i<8;i++){
            float w = d11[i*8+j];
            a0 += q1[i*3+0]*w; a1 += q1[i*3+1]*w; a2 += q1[i*3+2]*w;
        }
        qb[16+j*3+0]=QT1S*a0; qb[16+j*3+1]=QT1S*a1; qb[16+j*3+2]=QT1S*a2;
    }
}

// ---------------- edge_tp accumulation over 16 h-rows staged in LDS ----------------
__device__ __forceinline__ void tp_accum16(const float* __restrict__ w2,   // LDS [16][576]
                                           const float* __restrict__ w1,   // LDS [10][32]
                                           int h0,
                                           const float* __restrict__ emb,
                                           const float* __restrict__ x0,
                                           const float* __restrict__ x1,
                                           const float* __restrict__ x1s,
                                           float* __restrict__ o0,
                                           float* __restrict__ t8,
                                           float* __restrict__ u)
{
#pragma unroll 1
    for (int hh = 0; hh < 16; ++hh){
        float sacc = 0.f;
#pragma unroll
        for (int b = 0; b < 10; ++b) sacc += emb[b]*w1[b*32 + h0 + hh];
        float hk = __fdividef(sacc, 1.f + __expf(-sacc));     // silu
        const float* wr = w2 + hh*576;
        float g[16];
#pragma unroll
        for (int o=0;o<16;o++) g[o]=0.f;
#pragma unroll
        for (int i=0;i<16;i++){            // w00: cols 0..255, [i*16+o]
            float xi = x0[i];
#pragma unroll
            for (int o=0;o<16;o++) g[o] += xi*wr[i*16+o];
        }
#pragma unroll
        for (int i=0;i<8;i++){             // w11: cols 256..383
            float xi = x1s[i];
#pragma unroll
            for (int o=0;o<16;o++) g[o] += xi*wr[256+i*16+o];
        }
#pragma unroll
        for (int o=0;o<16;o++) o0[o] += hk*g[o];
        float g8[8];
#pragma unroll
        for (int o=0;o<8;o++) g8[o]=0.f;
#pragma unroll
        for (int i=0;i<16;i++){            // w01: cols 384..511, [i*8+o]
            float xi = x0[i];
#pragma unroll
            for (int o=0;o<8;o++) g8[o] += xi*wr[384+i*8+o];
        }
#pragma unroll
        for (int o=0;o<8;o++) t8[o] += hk*g8[o];
        float ga[8], gb[8], gc[8];
#pragma unroll
        for (int o=0;o<8;o++){ ga[o]=0.f; gb[o]=0.f; gc[o]=0.f; }
#pragma unroll
        for (int i=0;i<8;i++){             // w10: cols 512..575, [i*8+o]
            float xa = x1[i*3+0], xb = x1[i*3+1], xc = x1[i*3+2];
#pragma unroll
            for (int o=0;o<8;o++){
                float w = wr[512+i*8+o];
                ga[o] += xa*w; gb[o] += xb*w; gc[o] += xc*w;
            }
        }
#pragma unroll
        for (int o=0;o<8;o++){
            u[o*3+0] += hk*ga[o];
            u[o*3+1] += hk*gb[o];
            u[o*3+2] += hk*gc[o];
        }
    }
}

// shared edge front-end: load geom + source features
__device__ __forceinline__ void edge_frontend(const float* __restrict__ ws, int e,
                                              int& s, int& d,
                                              float su[3], float emb[10], float& cut,
                                              float x0[16], float x1[24], float x1s[8],
                                              const int* __restrict__ esrc,
                                              const int* __restrict__ edst)
{
    s = esrc[e]; d = edst[e];
    edge_geom(ws + WS_POS, s, d, su, emb, cut);
    const float* xb = ws + WS_NODEX + s*40;
#pragma unroll
    for (int i=0;i<16;i++) x0[i]=xb[i];
#pragma unroll
    for (int i=0;i<24;i++) x1[i]=xb[16+i];
#pragma unroll
    for (int i=0;i<8;i++)
        x1s[i] = x1[i*3+0]*su[0] + x1[i*3+1]*su[1] + x1[i*3+2]*su[2];
}

// ---------------- K2: edge K pass -> expv, z ----------------
__global__ __launch_bounds__(256, 2)
void k_edge_k(const int* __restrict__ esrc, const int* __restrict__ edst,
              float* __restrict__ ws)
{
    __shared__ float w2s[16*576];
    __shared__ float w1s[320];
    int tid = threadIdx.x;
    for (int i=tid;i<320;i+=256) w1s[i]=ws[WS_FCK1 + i];

    int e = blockIdx.x*256 + tid;
    int s, d; float su[3], emb[10], cut, x0[16], x1[24], x1s[8];
    edge_frontend(ws, e, s, d, su, emb, cut, x0, x1, x1s, esrc, edst);

    float o0[16], t8[8], u[24];
#pragma unroll
    for (int o=0;o<16;o++) o0[o]=0.f;
#pragma unroll
    for (int o=0;o<8;o++) t8[o]=0.f;
#pragma unroll
    for (int c=0;c<24;c++) u[c]=0.f;

    for (int half=0; half<2; ++half){
        __syncthreads();
        for (int i=tid;i<9216;i+=256) w2s[i]=ws[WS_FCK2 + half*9216 + i];
        __syncthreads();
        tp_accum16(w2s, w1s, half*16, emb, x0, x1, x1s, o0, t8, u);
    }
#pragma unroll
    for (int o=0;o<8;o++){
#pragma unroll
        for (int dd=0;dd<3;dd++) u[o*3+dd] += t8[o]*su[dd];
    }
    float dot = 0.f;
    const float* qb = ws + WS_NODEQ + d*40;
#pragma unroll
    for (int c=0;c<16;c++) dot += qb[c]*o0[c];
#pragma unroll
    for (int c=0;c<24;c++) dot += qb[16+c]*u[c];
    float ex = cut * __expf(dot);
    ws[WS_EXPV + e] = ex;
    atomicAdd(&ws[WS_Z + d], ex);
}

// ---------------- K3: edge V pass + fused alpha scatter ----------------
__global__ __launch_bounds__(256, 2)
void k_edge_v(const int* __restrict__ esrc, const int* __restrict__ edst,
              float* __restrict__ ws)
{
    __shared__ float w2s[16*576];
    __shared__ float w1s[320];
    int tid = threadIdx.x;
    for (int i=tid;i<320;i+=256) w1s[i]=ws[WS_FCV1 + i];

    int e = blockIdx.x*256 + tid;
    int s, d; float su[3], emb[10], cut, x0[16], x1[24], x1s[8];
    edge_frontend(ws, e, s, d, su, emb, cut, x0, x1, x1s, esrc, edst);

    float o0[16], t8[8], u[24];
#pragma unroll
    for (int o=0;o<16;o++) o0[o]=0.f;
#pragma unroll
    for (int o=0;o<8;o++) t8[o]=0.f;
#pragma unroll
    for (int c=0;c<24;c++) u[c]=0.f;

    for (int half=0; half<2; ++half){
        __syncthreads();
        for (int i=tid;i<9216;i+=256) w2s[i]=ws[WS_FCV2 + half*9216 + i];
        __syncthreads();
        tp_accum16(w2s, w1s, half*16, emb, x0, x1, x1s, o0, t8, u);
    }
#pragma unroll
    for (int o=0;o<8;o++){
#pragma unroll
        for (int dd=0;dd<3;dd++) u[o*3+dd] += t8[o]*su[dd];
    }
    float zz = ws[WS_Z + d];
    zz = (zz == 0.f) ? 1.f : zz;
    float coef = sqrtf(__fdividef(ws[WS_EXPV + e], zz)) * TPNORM;
    float* ab = ws + WS_ATT + d*40;
#pragma unroll
    for (int o=0;o<16;o++) atomicAdd(&ab[o], coef*o0[o]);
#pragma unroll
    for (int c=0;c<24;c++) atomicAdd(&ab[16+c], coef*u[c]);
}

// ---------------- K4: reduced fcp pass (only psi channels 0..2 needed) ----------------
__global__ __launch_bounds__(256, 2)
void k_edge_p(const int* __restrict__ esrc, const int* __restrict__ edst,
              float* __restrict__ ws)
{
    __shared__ float wp[64*72];   // per h: [io(24)][o(3)]
    __shared__ float w1p[640];
    int tid = threadIdx.x;
    for (int i=tid;i<640;i+=256) w1p[i]=ws[WS_FCP1 + i];
    for (int idx=tid; idx<64*72; idx+=256){
        int h = idx/72, j = idx - h*72;
        int io = j/3, o = j - io*3;
        int col = (io<16) ? (io*32+o) : (512 + (io-16)*32 + o);  // w00 / w11 blocks
        wp[idx] = ws[WS_FCP2 + h*1152 + col];
    }
    int e = blockIdx.x*256 + tid;
    int s = esrc[e], d = edst[e];
    float su[3], emb[10], cut;
    edge_geom(ws + WS_POS, s, d, su, emb, cut);
    const float* ab = ws + WS_ATT + s*40;
    float acat[24];
#pragma unroll
    for (int i=0;i<16;i++) acat[i] = ab[i];
#pragma unroll
    for (int i=0;i<8;i++)
        acat[16+i] = ab[16+i*3+0]*su[0] + ab[16+i*3+1]*su[1] + ab[16+i*3+2]*su[2];
    __syncthreads();
    float p0=0.f,p1=0.f,p2=0.f;
#pragma unroll 1
    for (int h=0; h<64; ++h){
        float sgm = 0.f;
#pragma unroll
        for (int b=0;b<10;b++) sgm += emb[b]*w1p[b*64+h];
        float hp = __fdividef(sgm, 1.f + __expf(-sgm));
        const float* wr = wp + h*72;
        float g0=0.f,g1=0.f,g2=0.f;
#pragma unroll
        for (int i=0;i<24;i++){
            g0 += acat[i]*wr[i*3+0];
            g1 += acat[i]*wr[i*3+1];
            g2 += acat[i]*wr[i*3+2];
        }
        p0 += hp*g0; p1 += hp*g1; p2 += hp*g2;
    }
    float sc = cut * TPNORM;
    atomicAdd(&ws[WS_POT3 + d*3+0], sc*p0);
    atomicAdd(&ws[WS_POT3 + d*3+1], sc*p1);
    atomicAdd(&ws[WS_POT3 + d*3+2], sc*p2);
}

// ---------------- K5: curl + dtype-branched store ----------------
__global__ __launch_bounds__(256)
void k_finalize(const float* __restrict__ ws, const int* __restrict__ flag,
                void* __restrict__ out)
{
    int n = blockIdx.x*256 + threadIdx.x;
    int isb = *flag;
    const float* pt = ws + WS_POT3 + n*3;
    float p0=pt[0], p1=pt[1], p2=pt[2];
    float add0 = 0.1f*(p2-p1), add1 = 0.1f*(p0-p2), add2 = 0.1f*(p1-p0);
    const float* ab = ws + WS_ATT + n*40;
#pragma unroll
    for (int c=0;c<40;c++){
        float v = ab[c];
        if (c==0) v += add0;
        if (c==1) v += add1;
        if (c==2) v += add2;
        if (isb) ((__hip_bfloat16*)out)[n*40+c] = __float2bfloat16(v);
        else     ((float*)out)[n*40+c] = v;
    }
}

extern "C" void kernel_launch(void* const* d_in, const int* in_sizes, int n_in,
                              void* d_out, int out_size, void* d_ws, size_t ws_size,
                              hipStream_t stream)
{
    float* ws = (float*)d_ws;
    int* flag = (int*)(ws + WS_FLAG);
    const int* esrc = (const int*)d_in[2];
    const int* edst = (const int*)d_in[3];

    hipMemsetAsync(ws + WS_Z,    0, NNODES*sizeof(float), stream);
    hipMemsetAsync(ws + WS_ATT,  0, NNODES*40*sizeof(float), stream);
    hipMemsetAsync(ws + WS_POT3, 0, NNODES*3*sizeof(float), stream);

    k_detect<<<1, 256, 0, stream>>>(d_in[4], flag);
    k_convert_all<<<(WS_CVT_END+255)/256, 256, 0, stream>>>(
        d_in[0], d_in[1], d_in[4], d_in[5], d_in[6], d_in[7],
        d_in[8], d_in[9], d_in[10], d_in[11], d_in[12], d_in[13],
        flag, ws);

    k_node_prep<<<NNODES/256, 256, 0, stream>>>(ws);
    k_edge_k<<<NEDGES/256, 256, 0, stream>>>(esrc, edst, ws);
    k_edge_v<<<NEDGES/256, 256, 0, stream>>>(esrc, edst, ws);
    k_edge_p<<<NEDGES/256, 256, 0, stream>>>(esrc, edst, ws);
    k_finalize<<<NNODES/256, 256, 0, stream>>>(ws, flag, d_out);
}

// Round 5
// 571.452 us; speedup vs baseline: 1.1512x; 1.1512x over previous
//
#include <hip/hip_runtime.h>
#include <hip/hip_bf16.h>
#include <math.h>

#define NNODES 8192
#define NEDGES 98304

#define TPNORM 0.20412414523193154f      // 1/sqrt(24)
#define INV_SQRT8 0.35355339059327373f   // 1/sqrt(8)
#define QT0S (1.0f/24.0f)                // dot-norm * tp-norm folded
#define QT1S 0.024056261216234406f       // 1/(24*sqrt(3))
#define EMB_C 26.6692997f                // 1.14136*e^2*sqrt(10)
#define STEPI 3.6666666666666665f        // 11/3

// ---- f32 workspace layout (dword offsets) ----
#define WS_NF    0
#define WS_POS   327680
#define WS_WQ0   352256
#define WS_WQ1   352512
#define WS_FCK1  352576
#define WS_FCK2  352896
#define WS_FCV1  371328
#define WS_FCV2  371648
#define WS_WD00  390080
#define WS_WD11  390336
#define WS_FCP1  390400
#define WS_FCP2  391040
#define WS_CVT_END 464768
#define WS_FLAG   464768
#define WS_NODEX  464784
#define WS_NODEQ  792464
#define WS_ZINV  1120144
#define WS_EXPV  1128336
#define WS_ATT   1226640
#define WS_COEF  1554320
#define WS_P3    1652624
#define WS_W2TK  1947536
#define WS_W2TV  1956752
#define WS_WPT   1965968
#define WS_CNT   1968528
#define WS_ROWPTR 1976720
#define WS_CURSOR 1984920
#define WS_EORDER 1993112
#define WS_VFLATB 2091416
// end 4057496 dwords = 16.23 MB

using s8v = __attribute__((ext_vector_type(8))) short;   // 8 bf16 (4 VGPRs)
using f4v = __attribute__((ext_vector_type(4))) float;

__device__ __forceinline__ short f2bf(float f){
    unsigned u = __float_as_uint(f);
    unsigned r = (u + 0x7fffu + ((u >> 16) & 1u)) >> 16;
    return (short)r;
}
__device__ __forceinline__ float bfbits2f(unsigned short u){
    return __uint_as_float(((unsigned int)u) << 16);
}

__device__ __forceinline__ float sus_f(float x){
    return x > 0.f ? __expf(-__fdividef(1.f, x)) : 0.f;
}

__device__ __forceinline__ void edge_geom(const float* __restrict__ pos,
                                          int s, int d,
                                          float su[3], float emb[10], float& cut)
{
    float ev[3];
#pragma unroll
    for (int c = 0; c < 3; ++c)
        ev[c] = pos[s*3+c] - pos[d*3+c];
    float l2 = ev[0]*ev[0] + ev[1]*ev[1] + ev[2]*ev[2] + 1e-12f;
    float elen = sqrtf(l2);
    float inv = __fdividef(1.f, elen);
#pragma unroll
    for (int c = 0; c < 3; ++c) su[c] = ev[c]*inv;
    float le = elen * STEPI;
#pragma unroll
    for (int k = 0; k < 10; ++k){
        float diff = le - (float)(k+1);
        emb[k] = EMB_C * sus_f(diff + 1.f) * sus_f(1.f - diff);
    }
    cut = sus_f(10.f * (1.f - elen*(1.f/3.f)));
}

// ---------------- K0: dtype detection (Wq0 ~ N(0,1), 256 samples) ----------------
__global__ void k_detect(const void* __restrict__ wq0raw, int* __restrict__ flag)
{
    __shared__ int cb;
    if (threadIdx.x == 0) cb = 0;
    __syncthreads();
    int t = threadIdx.x;
    const unsigned short* ph = (const unsigned short*)wq0raw;
    float v = bfbits2f(ph[t]);
    float a = fabsf(v);
    if (v == v && a > 1e-3f && a < 64.f) atomicAdd(&cb, 1);
    __syncthreads();
    if (threadIdx.x == 0) *flag = (cb >= 200) ? 1 : 0;
}

// ---------------- K0b: convert all float inputs to f32 in ws ----------------
__global__ __launch_bounds__(256)
void k_convert_all(const void* __restrict__ nf,   const void* __restrict__ pos,
                   const void* __restrict__ wq0,  const void* __restrict__ wq1,
                   const void* __restrict__ fck1, const void* __restrict__ fck2,
                   const void* __restrict__ fcv1, const void* __restrict__ fcv2,
                   const void* __restrict__ wd00, const void* __restrict__ wd11,
                   const void* __restrict__ fcp1, const void* __restrict__ fcp2,
                   const int* __restrict__ flag,  float* __restrict__ dst)
{
    int idx = blockIdx.x*256 + threadIdx.x;
    if (idx >= WS_CVT_END) return;
    int isb = *flag;
    const void* src; int local;
    if      (idx < WS_POS)  { src = nf;   local = idx; }
    else if (idx < WS_WQ0)  { src = pos;  local = idx - WS_POS; }
    else if (idx < WS_WQ1)  { src = wq0;  local = idx - WS_WQ0; }
    else if (idx < WS_FCK1) { src = wq1;  local = idx - WS_WQ1; }
    else if (idx < WS_FCK2) { src = fck1; local = idx - WS_FCK1; }
    else if (idx < WS_FCV1) { src = fck2; local = idx - WS_FCK2; }
    else if (idx < WS_FCV2) { src = fcv1; local = idx - WS_FCV1; }
    else if (idx < WS_WD00) { src = fcv2; local = idx - WS_FCV2; }
    else if (idx < WS_WD11) { src = wd00; local = idx - WS_WD00; }
    else if (idx < WS_FCP1) { src = wd11; local = idx - WS_WD11; }
    else if (idx < WS_FCP2) { src = fcp1; local = idx - WS_FCP1; }
    else                    { src = fcp2; local = idx - WS_FCP2; }
    float v;
    if (isb){
        v = bfbits2f(((const unsigned short*)src)[local]);
    } else {
        v = ((const float*)src)[local];
    }
    dst[idx] = v;
}

// ---------------- K0c: build bf16 wpt table for MFMA edge_p ----------------
// wpt: [col(80 pad)][k(64)] bf16 (fcp psi cols, compacted col = io*3+o)
__global__ __launch_bounds__(256)
void k_prep_w2t(float* __restrict__ ws)
{
    int idx = blockIdx.x*256 + threadIdx.x;   // 5120 total
    if (idx >= 5120) return;
    unsigned short* wpt  = (unsigned short*)(ws + WS_WPT);
    int c = idx >> 6, h = idx & 63;
    unsigned short v = 0;
    if (c < 72){
        int io = c / 3, o = c - io*3;
        int col = (io < 16) ? (io*32 + o) : (512 + (io-16)*32 + o);
        v = (unsigned short)f2bf(ws[WS_FCP2 + h*1152 + col]);
    }
    wpt[idx] = v;
}

// ---------------- CSR build: hist / scan / scatter ----------------
__global__ __launch_bounds__(256)
void k_hist(const int* __restrict__ edst, int* __restrict__ cnt)
{
    int e = blockIdx.x*256 + threadIdx.x;
    atomicAdd(&cnt[edst[e]], 1);
}

__global__ __launch_bounds__(1024)
void k_scan(const int* __restrict__ cnt, int* __restrict__ rowptr, int* __restrict__ cursor)
{
    __shared__ int sdata[1024];
    int tid = threadIdx.x;
    int base = tid*8;
    int loc[8]; int s = 0;
#pragma unroll
    for (int i=0;i<8;i++){ loc[i] = s; s += cnt[base+i]; }
    sdata[tid] = s;
    __syncthreads();
    for (int off=1; off<1024; off<<=1){
        int t = (tid >= off) ? sdata[tid-off] : 0;
        __syncthreads();
        sdata[tid] += t;
        __syncthreads();
    }
    int excl = sdata[tid] - s;
#pragma unroll
    for (int i=0;i<8;i++){
        int v = excl + loc[i];
        rowptr[base+i] = v;
        cursor[base+i] = v;
    }
    if (tid == 1023) rowptr[8192] = sdata[1023];
}

__global__ __launch_bounds__(256)
void k_scatter(const int* __restrict__ edst, int* __restrict__ cursor, int* __restrict__ eorder)
{
    int e = blockIdx.x*256 + threadIdx.x;
    int p = atomicAdd(&cursor[edst[e]], 1);
    eorder[p] = e;
}

// ---------------- K1: node prep ----------------
__global__ __launch_bounds__(256)
void k_node_prep(float* __restrict__ ws)
{
    __shared__ float q0w[256], d00[256], q1w[64], d11[64];
    int tid = threadIdx.x;
    q0w[tid] = ws[WS_WQ0 + tid];
    d00[tid] = ws[WS_WD00 + tid];
    if (tid < 64){ q1w[tid] = ws[WS_WQ1 + tid]; d11[tid] = ws[WS_WD11 + tid]; }
    __syncthreads();
    int n = blockIdx.x*256 + tid;
    const float* fb = ws + WS_NF + n*40;
    float x0[16], x1[24];
#pragma unroll
    for (int i=0;i<16;i++) x0[i]=fb[i];
#pragma unroll
    for (int i=0;i<24;i++) x1[i]=fb[16+i];
    float q0[16];
#pragma unroll
    for (int o=0;o<16;o++){
        float a=0.f;
#pragma unroll
        for (int i=0;i<16;i++) a += x0[i]*q0w[i*16+o];
        q0[o] = 0.25f*a;
    }
    float q1[24];
#pragma unroll
    for (int o=0;o<8;o++){
        float a0=0.f,a1=0.f,a2=0.f;
#pragma unroll
        for (int i=0;i<8;i++){
            float w = q1w[i*8+o];
            a0 += x1[i*3+0]*w; a1 += x1[i*3+1]*w; a2 += x1[i*3+2]*w;
        }
        q1[o*3+0]=INV_SQRT8*a0; q1[o*3+1]=INV_SQRT8*a1; q1[o*3+2]=INV_SQRT8*a2;
    }
    float* xb = ws + WS_NODEX + n*40;
#pragma unroll
    for (int i=0;i<16;i++) xb[i]=x0[i];
#pragma unroll
    for (int i=0;i<24;i++) xb[16+i]=x1[i];
    float* qb = ws + WS_NODEQ + n*40;
#pragma unroll
    for (int j=0;j<16;j++){
        float a=0.f;
#pragma unroll
        for (int i=0;i<16;i++) a += q0[i]*d00[i*16+j];
        qb[j] = QT0S*a;
    }
#pragma unroll
    for (int j=0;j<8;j++){
        float a0=0.f,a1=0.f,a2=0.f;
#pragma unroll
        for (int i=0;i<8;i++){
            float w = d11[i*8+j];
            a0 += q1[i*3+0]*w; a1 += q1[i*3+1]*w; a2 += q1[i*3+2]*w;
        }
        qb[16+j*3+0]=QT1S*a0; qb[16+j*3+1]=QT1S*a1; qb[16+j*3+2]=QT1S*a2;
    }
}

// ---------------- scalar edge_tp accumulation (R2-proven) ----------------
__device__ __forceinline__ void tp_accum16(const float* __restrict__ w2,   // LDS [16][576]
                                           const float* __restrict__ w1,   // LDS [10][32]
                                           int h0,
                                           const float* __restrict__ emb,
                                           const float* __restrict__ x0,
                                           const float* __restrict__ x1,
                                           const float* __restrict__ x1s,
                                           float* __restrict__ o0,
                                           float* __restrict__ t8,
                                           float* __restrict__ u)
{
#pragma unroll 1
    for (int hh = 0; hh < 16; ++hh){
        float sacc = 0.f;
#pragma unroll
        for (int b = 0; b < 10; ++b) sacc += emb[b]*w1[b*32 + h0 + hh];
        float hk = __fdividef(sacc, 1.f + __expf(-sacc));     // silu
        const float* wr = w2 + hh*576;
        float g[16];
#pragma unroll
        for (int o=0;o<16;o++) g[o]=0.f;
#pragma unroll
        for (int i=0;i<16;i++){            // w00: cols 0..255, [i*16+o]
            float xi = x0[i];
#pragma unroll
            for (int o=0;o<16;o++) g[o] += xi*wr[i*16+o];
        }
#pragma unroll
        for (int i=0;i<8;i++){             // w11: cols 256..383
            float xi = x1s[i];
#pragma unroll
            for (int o=0;o<16;o++) g[o] += xi*wr[256+i*16+o];
        }
#pragma unroll
        for (int o=0;o<16;o++) o0[o] += hk*g[o];
        float g8[8];
#pragma unroll
        for (int o=0;o<8;o++) g8[o]=0.f;
#pragma unroll
        for (int i=0;i<16;i++){            // w01: cols 384..511, [i*8+o]
            float xi = x0[i];
#pragma unroll
            for (int o=0;o<8;o++) g8[o] += xi*wr[384+i*8+o];
        }
#pragma unroll
        for (int o=0;o<8;o++) t8[o] += hk*g8[o];
        float ga[8], gb[8], gc[8];
#pragma unroll
        for (int o=0;o<8;o++){ ga[o]=0.f; gb[o]=0.f; gc[o]=0.f; }
#pragma unroll
        for (int i=0;i<8;i++){             // w10: cols 512..575, [i*8+o]
            float xa = x1[i*3+0], xb = x1[i*3+1], xc = x1[i*3+2];
#pragma unroll
            for (int o=0;o<8;o++){
                float w = wr[512+i*8+o];
                ga[o] += xa*w; gb[o] += xb*w; gc[o] += xc*w;
            }
        }
#pragma unroll
        for (int o=0;o<8;o++){
            u[o*3+0] += hk*ga[o];
            u[o*3+1] += hk*gb[o];
            u[o*3+2] += hk*gc[o];
        }
    }
}

__device__ __forceinline__ void edge_frontend(const float* __restrict__ ws, int e,
                                              int& s, int& d,
                                              float su[3], float emb[10], float& cut,
                                              float x0[16], float x1[24], float x1s[8],
                                              const int* __restrict__ esrc,
                                              const int* __restrict__ edst)
{
    s = esrc[e]; d = edst[e];
    edge_geom(ws + WS_POS, s, d, su, emb, cut);
    const float* xb = ws + WS_NODEX + s*40;
#pragma unroll
    for (int i=0;i<16;i++) x0[i]=xb[i];
#pragma unroll
    for (int i=0;i<24;i++) x1[i]=xb[16+i];
#pragma unroll
    for (int i=0;i<8;i++)
        x1s[i] = x1[i*3+0]*su[0] + x1[i*3+1]*su[1] + x1[i*3+2]*su[2];
}

// ---------------- K2: scalar edge K pass -> expv (no atomics) ----------------
__global__ __launch_bounds__(256, 2)
void k_edge_k(const int* __restrict__ esrc, const int* __restrict__ edst,
              float* __restrict__ ws)
{
    __shared__ float w2s[16*576];
    __shared__ float w1s[320];
    int tid = threadIdx.x;
    for (int i=tid;i<320;i+=256) w1s[i]=ws[WS_FCK1 + i];

    int e = blockIdx.x*256 + tid;
    int s, d; float su[3], emb[10], cut, x0[16], x1[24], x1s[8];
    edge_frontend(ws, e, s, d, su, emb, cut, x0, x1, x1s, esrc, edst);

    float o0[16], t8[8], u[24];
#pragma unroll
    for (int o=0;o<16;o++) o0[o]=0.f;
#pragma unroll
    for (int o=0;o<8;o++) t8[o]=0.f;
#pragma unroll
    for (int c=0;c<24;c++) u[c]=0.f;

    for (int half=0; half<2; ++half){
        __syncthreads();
        for (int i=tid;i<9216;i+=256) w2s[i]=ws[WS_FCK2 + half*9216 + i];
        __syncthreads();
        tp_accum16(w2s, w1s, half*16, emb, x0, x1, x1s, o0, t8, u);
    }
#pragma unroll
    for (int o=0;o<8;o++){
#pragma unroll
        for (int dd=0;dd<3;dd++) u[o*3+dd] += t8[o]*su[dd];
    }
    float dot = 0.f;
    const float* qb = ws + WS_NODEQ + d*40;
#pragma unroll
    for (int c=0;c<16;c++) dot += qb[c]*o0[c];
#pragma unroll
    for (int c=0;c<24;c++) dot += qb[16+c]*u[c];
    ws[WS_EXPV + e] = cut * __expf(dot);
}

// ---------------- K3: scalar edge V pass -> f16 vflat (no atomics) ----------------
__global__ __launch_bounds__(256, 2)
void k_edge_v(const int* __restrict__ esrc, const int* __restrict__ edst,
              float* __restrict__ ws)
{
    __shared__ float w2s[16*576];
    __shared__ float w1s[320];
    int tid = threadIdx.x;
    for (int i=tid;i<320;i+=256) w1s[i]=ws[WS_FCV1 + i];

    int e = blockIdx.x*256 + tid;
    int s, d; float su[3], emb[10], cut, x0[16], x1[24], x1s[8];
    edge_frontend(ws, e, s, d, su, emb, cut, x0, x1, x1s, esrc, edst);

    float o0[16], t8[8], u[24];
#pragma unroll
    for (int o=0;o<16;o++) o0[o]=0.f;
#pragma unroll
    for (int o=0;o<8;o++) t8[o]=0.f;
#pragma unroll
    for (int c=0;c<24;c++) u[c]=0.f;

    for (int half=0; half<2; ++half){
        __syncthreads();
        for (int i=tid;i<9216;i+=256) w2s[i]=ws[WS_FCV2 + half*9216 + i];
        __syncthreads();
        tp_accum16(w2s, w1s, half*16, emb, x0, x1, x1s, o0, t8, u);
    }
#pragma unroll
    for (int o=0;o<8;o++){
#pragma unroll
        for (int dd=0;dd<3;dd++) u[o*3+dd] += t8[o]*su[dd];
    }
    // raw values (TPNORM folded into coef), f16 row-major per edge
    _Float16* vfb = (_Float16*)(ws + WS_VFLATB);
    size_t idx = (size_t)e * 40;
#pragma unroll
    for (int o=0;o<16;o++) vfb[idx + o] = (_Float16)o0[o];
#pragma unroll
    for (int c=0;c<24;c++) vfb[idx + 16 + c] = (_Float16)u[c];
}

// ---------------- K3a: z (CSR gather) ----------------
__global__ __launch_bounds__(256)
void k_zinv(float* __restrict__ ws)
{
    int n = blockIdx.x*256 + threadIdx.x;
    const int* rowptr = (const int*)(ws + WS_ROWPTR);
    const int* eorder = (const int*)(ws + WS_EORDER);
    int a = rowptr[n], b = rowptr[n+1];
    float sum = 0.f;
    for (int j=a; j<b; ++j) sum += ws[WS_EXPV + eorder[j]];
    ws[WS_ZINV + n] = (sum == 0.f) ? 1.f : __fdividef(1.f, sum);
}

// ---------------- K3b: per-edge coef ----------------
__global__ __launch_bounds__(256)
void k_coef(const int* __restrict__ edst, float* __restrict__ ws)
{
    int e = blockIdx.x*256 + threadIdx.x;
    ws[WS_COEF + e] = sqrtf(ws[WS_EXPV + e] * ws[WS_ZINV + edst[e]]) * TPNORM;
}

// ---------------- K3c: att gather (no atomics) ----------------
__global__ __launch_bounds__(256)
void k_attgather(float* __restrict__ ws)
{
    int t = blockIdx.x*256 + threadIdx.x;   // 327680 = 8192*40
    int d = t / 40;
    int c = t - d*40;
    const int* rowptr = (const int*)(ws + WS_ROWPTR);
    const int* eorder = (const int*)(ws + WS_EORDER);
    const _Float16* vfb = (const _Float16*)(ws + WS_VFLATB);
    int a = rowptr[d], b = rowptr[d+1];
    float acc = 0.f;
    for (int j=a; j<b; ++j){
        int e = eorder[j];
        acc += ws[WS_COEF + e] * (float)vfb[(size_t)e*40 + c];
    }
    ws[WS_ATT + t] = acc;
}

// ------- silu A-fragment builder, SPLIT precision: hk = ah + al (bf16 pair) -------
__device__ __forceinline__ void build_A2(const float* __restrict__ w1, int w1stride,
                                         const float emb[10], int quad, int hbase,
                                         s8v& ah, s8v& al)
{
#pragma unroll
    for (int j=0;j<8;j++){
        int h = hbase + quad*8 + j;
        float sacc = 0.f;
#pragma unroll
        for (int b=0;b<10;b++) sacc += emb[b]*w1[b*w1stride + h];
        float sl = __fdividef(sacc, 1.f + __expf(-sacc));
        short hi = f2bf(sl);
        float rem = sl - bfbits2f((unsigned short)hi);
        ah[j] = hi;
        al[j] = f2bf(rem);
    }
}

// ---------------- K4: fcp psi pass (MFMA, K=64, 72 useful cols) ----------------
#define PA_ACAT 0
#define PA_CUT  384
__global__ __launch_bounds__(256, 4)
void k_edge_p(const int* __restrict__ esrc, const int* __restrict__ edst,
              float* __restrict__ ws)
{
    __shared__ float w1p[640];
    __shared__ float pbuf[4][400];
    const int tid = threadIdx.x;
    for (int i=tid;i<640;i+=256) w1p[i] = ws[WS_FCP1 + i];
    const int wid = tid>>6, lane = tid&63;
    const int m = lane&15, quad = lane>>4;
    const int ebase = blockIdx.x*64 + wid*16;
    const int e = ebase + m;
    const int s = esrc[e], d = edst[e];
    float su[3], emb[10], cut;
    edge_geom(ws + WS_POS, s, d, su, emb, cut);
    float* wb = pbuf[wid];
#pragma unroll
    for (int t=0;t<6;t++){
        int io = quad*6 + t;
        float v;
        if (io < 16) v = ws[WS_ATT + s*40 + io];
        else {
            int i1 = io - 16;
            v = ws[WS_ATT + s*40 + 16 + i1*3 + 0]*su[0]
              + ws[WS_ATT + s*40 + 16 + i1*3 + 1]*su[1]
              + ws[WS_ATT + s*40 + 16 + i1*3 + 2]*su[2];
        }
        wb[PA_ACAT + io*16 + m] = v;
    }
    if (quad == 0) wb[PA_CUT + m] = cut;
    __syncthreads();

    s8v a0h, a0l, a1h, a1l;
    build_A2(w1p, 64, emb, quad, 0,  a0h, a0l);
    build_A2(w1p, 64, emb, quad, 32, a1h, a1l);
    const unsigned short* wpt = (const unsigned short*)(ws + WS_WPT);
    const f4v zero = {0.f,0.f,0.f,0.f};
    float pa[4][3];
#pragma unroll
    for (int r=0;r<4;r++){ pa[r][0]=0.f; pa[r][1]=0.f; pa[r][2]=0.f; }
#pragma unroll
    for (int ch=0; ch<5; ++ch){
        int col = ch*16 + m;
        s8v b0 = *(const s8v*)(wpt + col*64 + quad*8);
        s8v b1 = *(const s8v*)(wpt + col*64 + 32 + quad*8);
        f4v c = __builtin_amdgcn_mfma_f32_16x16x32_bf16(a0l, b0, zero, 0, 0, 0);
        c = __builtin_amdgcn_mfma_f32_16x16x32_bf16(a1l, b1, c, 0, 0, 0);
        c = __builtin_amdgcn_mfma_f32_16x16x32_bf16(a0h, b0, c, 0, 0, 0);
        c = __builtin_amdgcn_mfma_f32_16x16x32_bf16(a1h, b1, c, 0, 0, 0);
        bool valid = col < 72;
        int io = valid ? ((col*2731) >> 13) : 0;
        int o = col - io*3;
        f4v xv = *(const f4v*)(wb + PA_ACAT + io*16 + quad*4);
#pragma unroll
        for (int r=0;r<4;r++){
            float vv = valid ? xv[r]*c[r] : 0.f;
            pa[r][0] += (o==0) ? vv : 0.f;
            pa[r][1] += (o==1) ? vv : 0.f;
            pa[r][2] += (o==2) ? vv : 0.f;
        }
    }
#pragma unroll
    for (int off=1; off<16; off<<=1){
#pragma unroll
        for (int r=0;r<4;r++){
            pa[r][0] += __shfl_xor(pa[r][0], off);
            pa[r][1] += __shfl_xor(pa[r][1], off);
            pa[r][2] += __shfl_xor(pa[r][2], off);
        }
    }
    if (m == 0){
#pragma unroll
        for (int r=0;r<4;r++){
            int er = quad*4 + r;
            float sc = wb[PA_CUT + er] * TPNORM;
#pragma unroll
            for (int k=0;k<3;k++) ws[WS_P3 + (size_t)(ebase+er)*3 + k] = sc*pa[r][k];
        }
    }
}

// ---------------- K5: pot gather + curl + store ----------------
__global__ __launch_bounds__(256)
void k_potfin(float* __restrict__ ws, const int* __restrict__ flag, void* __restrict__ out)
{
    int n = blockIdx.x*256 + threadIdx.x;
    const int* rowptr = (const int*)(ws + WS_ROWPTR);
    const int* eorder = (const int*)(ws + WS_EORDER);
    int a = rowptr[n], b = rowptr[n+1];
    float s0=0.f, s1=0.f, s2=0.f;
    for (int j=a; j<b; ++j){
        int e = eorder[j];
        s0 += ws[WS_P3 + (size_t)e*3 + 0];
        s1 += ws[WS_P3 + (size_t)e*3 + 1];
        s2 += ws[WS_P3 + (size_t)e*3 + 2];
    }
    float add0 = 0.1f*(s2-s1), add1 = 0.1f*(s0-s2), add2 = 0.1f*(s1-s0);
    int isb = *flag;
    const float* ab = ws + WS_ATT + (size_t)n*40;
#pragma unroll
    for (int c=0;c<40;c++){
        float v = ab[c];
        if (c==0) v += add0;
        if (c==1) v += add1;
        if (c==2) v += add2;
        if (isb) ((__hip_bfloat16*)out)[(size_t)n*40+c] = __float2bfloat16(v);
        else     ((float*)out)[(size_t)n*40+c] = v;
    }
}

extern "C" void kernel_launch(void* const* d_in, const int* in_sizes, int n_in,
                              void* d_out, int out_size, void* d_ws, size_t ws_size,
                              hipStream_t stream)
{
    float* ws = (float*)d_ws;
    int* flag = (int*)(ws + WS_FLAG);
    const int* esrc = (const int*)d_in[2];
    const int* edst = (const int*)d_in[3];

    hipMemsetAsync(ws + WS_CNT, 0, 8192*sizeof(int), stream);

    k_detect<<<1, 256, 0, stream>>>(d_in[4], flag);
    k_convert_all<<<(WS_CVT_END+255)/256, 256, 0, stream>>>(
        d_in[0], d_in[1], d_in[4], d_in[5], d_in[6], d_in[7],
        d_in[8], d_in[9], d_in[10], d_in[11], d_in[12], d_in[13],
        flag, ws);
    k_prep_w2t<<<20, 256, 0, stream>>>(ws);

    k_hist<<<NEDGES/256, 256, 0, stream>>>(edst, (int*)(ws + WS_CNT));
    k_scan<<<1, 1024, 0, stream>>>((const int*)(ws + WS_CNT),
                                   (int*)(ws + WS_ROWPTR), (int*)(ws + WS_CURSOR));
    k_scatter<<<NEDGES/256, 256, 0, stream>>>(edst, (int*)(ws + WS_CURSOR),
                                              (int*)(ws + WS_EORDER));

    k_node_prep<<<NNODES/256, 256, 0, stream>>>(ws);
    k_edge_k<<<NEDGES/256, 256, 0, stream>>>(esrc, edst, ws);
    k_edge_v<<<NEDGES/256, 256, 0, stream>>>(esrc, edst, ws);
    k_zinv<<<NNODES/256, 256, 0, stream>>>(ws);
    k_coef<<<NEDGES/256, 256, 0, stream>>>(edst, ws);
    k_attgather<<<(NNODES*40)/256, 256, 0, stream>>>(ws);
    k_edge_p<<<NEDGES/64, 256, 0, stream>>>(esrc, edst, ws);
    k_potfin<<<NNODES/256, 256, 0, stream>>>(ws, flag, d_out);
}